// Round 1
// baseline (302.678 us; speedup 1.0000x reference)
//
#include <hip/hip_runtime.h>
#include <math.h>

// Soft-MoE forward, fp32 throughout.
// B=8, M=4096, D=512, E=64, P=1, H=2048.
// Pipeline: rownorm -> phinorm -> logits GEMM (invn folded) -> d-softmax stats
// -> dispatch (xs, 32 m-splits) -> xs reduce (/dsum) -> MLP1 (w1, 4 d-splits)
// -> gelu reduce -> MLP2 (w2, 8 k-splits) -> ys reduce (+b2) -> combine (c softmax + y).
// ws requirement: ~73.8 MB (see WS_FLOATS).

namespace {
constexpr int B = 8, M = 4096, D = 512, E = 64, H = 2048;
constexpr int NSD = 32;  // dstat m-splits (128 rows each)
constexpr int NSX = 32;  // dispatch m-splits
constexpr int NK1 = 4;   // gemm1 d-splits
constexpr int NK2 = 8;   // gemm2 k-splits

constexpr size_t OFF_INVN = 0;                            // B*M
constexpr size_t OFF_PHIN = OFF_INVN + (size_t)B * M;     // D*E
constexpr size_t OFF_LOG  = OFF_PHIN + (size_t)D * E;     // B*M*E (normalized logits)
constexpr size_t OFF_PMAX = OFF_LOG  + (size_t)B * M * E; // B*NSD*E
constexpr size_t OFF_PSUM = OFF_PMAX + (size_t)B * NSD * E;
constexpr size_t OFF_DMAX = OFF_PSUM + (size_t)B * NSD * E; // B*E
constexpr size_t OFF_DSUM = OFF_DMAX + (size_t)B * E;       // B*E
constexpr size_t OFF_XSP  = OFF_DSUM + (size_t)B * E;       // NSX*B*E*D
constexpr size_t OFF_XSF  = OFF_XSP  + (size_t)NSX * B * E * D; // E*D*B
constexpr size_t OFF_HP   = OFF_XSF  + (size_t)E * D * B;   // NK1*E*H*B
constexpr size_t OFF_HT   = OFF_HP   + (size_t)NK1 * E * H * B; // E*H*B
constexpr size_t OFF_YSP  = OFF_HT   + (size_t)E * H * B;   // NK2*E*D*B
constexpr size_t OFF_YSF  = OFF_YSP  + (size_t)NK2 * E * D * B; // B*E*D ([b][e][d])
constexpr size_t WS_FLOATS = OFF_YSF + (size_t)E * D * B;
} // namespace

// ---- K1: per-token inverse L2 norm. grid 8192, block 256 (wave per row) ----
__global__ __launch_bounds__(256) void k_rownorm(const float* __restrict__ x,
                                                 float* __restrict__ invn) {
  int row  = blockIdx.x * 4 + (threadIdx.x >> 6);
  int lane = threadIdx.x & 63;
  const float4* xr = (const float4*)(x + (size_t)row * D);
  float4 v0 = xr[lane];
  float4 v1 = xr[lane + 64];
  float ss = v0.x * v0.x + v0.y * v0.y + v0.z * v0.z + v0.w * v0.w +
             v1.x * v1.x + v1.y * v1.y + v1.z * v1.z + v1.w * v1.w;
#pragma unroll
  for (int off = 32; off; off >>= 1) ss += __shfl_down(ss, off, 64);
  if (lane == 0) invn[row] = 1.0f / fmaxf(sqrtf(ss), 1e-12f);
}

// ---- K2: phin = scale * l2norm(phi, axis=0). grid 64 (one col), block 256 ----
__global__ __launch_bounds__(256) void k_phinorm(const float* __restrict__ phi,
                                                 const float* __restrict__ scale,
                                                 float* __restrict__ phin) {
  int e = blockIdx.x;
  int t = threadIdx.x;
  float v0 = phi[(size_t)t * E + e];
  float v1 = phi[(size_t)(t + 256) * E + e];
  __shared__ float red[256];
  red[t] = v0 * v0 + v1 * v1;
  __syncthreads();
  for (int s = 128; s; s >>= 1) {
    if (t < s) red[t] += red[t + s];
    __syncthreads();
  }
  float inv = scale[0] / fmaxf(sqrtf(red[0]), 1e-12f);
  phin[(size_t)t * E + e]         = v0 * inv;
  phin[(size_t)(t + 256) * E + e] = v1 * inv;
}

// ---- K3: logits[row][e] = invn[row] * sum_d x[row][d]*phin[d][e] ----
// grid 256 (128-row tiles), block 256; thread tile 8 rows x 4 e.
__global__ __launch_bounds__(256) void k_logits(const float* __restrict__ x,
                                                const float* __restrict__ phin,
                                                const float* __restrict__ invn,
                                                float* __restrict__ logits) {
  __shared__ float xT[16][132];
  __shared__ float ph[16][68];
  __shared__ float invs[128];
  int t = threadIdx.x;
  int rowbase = blockIdx.x * 128;
  if (t < 128) invs[t] = invn[rowbase + t];
  float acc[8][4];
#pragma unroll
  for (int i = 0; i < 8; i++)
#pragma unroll
    for (int j = 0; j < 4; j++) acc[i][j] = 0.f;
  int r0 = (t & 15) * 8;    // 0..120
  int e0 = (t >> 4) * 4;    // 0..60
  int srow = t >> 1;        // 0..127
  int sdh  = (t & 1) * 8;   // 0 or 8
  int pd = t >> 4;          // 0..15
  int pe = (t & 15) * 4;    // 0..60
  for (int d0 = 0; d0 < D; d0 += 16) {
    __syncthreads();
    const float4* xp = (const float4*)(x + (size_t)(rowbase + srow) * D + d0 + sdh);
    float4 a = xp[0], b = xp[1];
    xT[sdh + 0][srow] = a.x; xT[sdh + 1][srow] = a.y;
    xT[sdh + 2][srow] = a.z; xT[sdh + 3][srow] = a.w;
    xT[sdh + 4][srow] = b.x; xT[sdh + 5][srow] = b.y;
    xT[sdh + 6][srow] = b.z; xT[sdh + 7][srow] = b.w;
    *(float4*)&ph[pd][pe] = *(const float4*)(phin + (size_t)(d0 + pd) * E + pe);
    __syncthreads();
#pragma unroll 4
    for (int kk = 0; kk < 16; kk++) {
      float a8[8], b4[4];
      *(float4*)&a8[0] = *(float4*)&xT[kk][r0];
      *(float4*)&a8[4] = *(float4*)&xT[kk][r0 + 4];
      *(float4*)&b4[0] = *(float4*)&ph[kk][e0];
#pragma unroll
      for (int i = 0; i < 8; i++)
#pragma unroll
        for (int j = 0; j < 4; j++) acc[i][j] += a8[i] * b4[j];
    }
  }
#pragma unroll
  for (int i = 0; i < 8; i++) {
    float inv = invs[r0 + i];
    float4 o;
    o.x = acc[i][0] * inv; o.y = acc[i][1] * inv;
    o.z = acc[i][2] * inv; o.w = acc[i][3] * inv;
    *(float4*)(logits + (size_t)(rowbase + r0 + i) * E + e0) = o;
  }
}

// ---- K4: per (b, 128-row split, e): online max/sumexp over m ----
// grid B*NSD=256, block 256 (4 waves; lane=e, wave strides rows)
__global__ __launch_bounds__(256) void k_dstat(const float* __restrict__ logits,
                                               float* __restrict__ pmax,
                                               float* __restrict__ psum) {
  int blk = blockIdx.x;
  int b = blk >> 5, s = blk & 31;
  int t = threadIdx.x, e = t & 63, w = t >> 6;
  int m0 = s * 128;
  const float* Lp = logits + ((size_t)(b * M + m0)) * E + e;
  float mx = -1e30f, sm = 0.f;
  for (int r = w; r < 128; r += 4) {
    float v = Lp[(size_t)r * E];
    float nm = fmaxf(mx, v);
    sm = sm * __expf(mx - nm) + __expf(v - nm);
    mx = nm;
  }
  __shared__ float smax[4][64], ssum[4][64];
  smax[w][e] = mx; ssum[w][e] = sm;
  __syncthreads();
  if (t < 64) {
    float gm = smax[0][e];
    for (int i = 1; i < 4; i++) gm = fmaxf(gm, smax[i][e]);
    float gs = 0.f;
    for (int i = 0; i < 4; i++) gs += ssum[i][e] * __expf(smax[i][e] - gm);
    pmax[(size_t)blk * 64 + e] = gm;
    psum[(size_t)blk * 64 + e] = gs;
  }
}

// ---- K4b: combine split stats -> dmax/dsum. grid B, block 64 ----
__global__ __launch_bounds__(64) void k_dstat2(const float* __restrict__ pmax,
                                               const float* __restrict__ psum,
                                               float* __restrict__ dmax,
                                               float* __restrict__ dsum) {
  int b = blockIdx.x, e = threadIdx.x;
  float gm = -1e30f;
  for (int s = 0; s < NSD; s++) gm = fmaxf(gm, pmax[((size_t)(b * NSD + s)) * 64 + e]);
  float gs = 0.f;
  for (int s = 0; s < NSD; s++)
    gs += psum[((size_t)(b * NSD + s)) * 64 + e] *
          __expf(pmax[((size_t)(b * NSD + s)) * 64 + e] - gm);
  dmax[b * 64 + e] = gm;
  dsum[b * 64 + e] = gs;
}

// ---- K5: dispatch partial: xs_part[ms][b][e][d] = sum_{m in split} exp(L-dmax)*xn ----
// grid B*NSX*2=512 (dg = 256-col half), block 256; thread tile 8e x 8d.
__global__ __launch_bounds__(256) void k_dispatch(const float* __restrict__ x,
                                                  const float* __restrict__ logits,
                                                  const float* __restrict__ invn,
                                                  const float* __restrict__ dmax,
                                                  float* __restrict__ xs_part) {
  __shared__ float wexp[32][68];
  __shared__ float xt[32][260];
  __shared__ float dmx[64];
  int t = threadIdx.x;
  int blk = blockIdx.x;
  int dg = blk & 1, ms = (blk >> 1) & 31, b = blk >> 6;
  int m0 = ms * 128;
  if (t < 64) dmx[t] = dmax[b * 64 + t];
  float acc[8][8];
#pragma unroll
  for (int i = 0; i < 8; i++)
#pragma unroll
    for (int j = 0; j < 8; j++) acc[i][j] = 0.f;
  int e0 = (t & 7) * 8, d0 = (t >> 3) * 8;
  for (int c = 0; c < 4; c++) {
    int mr = m0 + c * 32;
    __syncthreads();
#pragma unroll
    for (int k = 0; k < 8; k++) {  // stage exp weights [32][64]
      int idx = t + 256 * k;
      int r = idx >> 6, e = idx & 63;
      wexp[r][e] = __expf(logits[((size_t)(b * M + mr + r)) * E + e] - dmx[e]);
    }
#pragma unroll
    for (int k = 0; k < 8; k++) {  // stage xn tile [32][256]
      int f4 = t + 256 * k;
      int r = f4 >> 6, ci = f4 & 63;
      float4 v = *(const float4*)(x + ((size_t)(b * M + mr + r)) * D + dg * 256 + ci * 4);
      float iv = invn[b * M + mr + r];
      v.x *= iv; v.y *= iv; v.z *= iv; v.w *= iv;
      *(float4*)&xt[r][ci * 4] = v;
    }
    __syncthreads();
#pragma unroll 2
    for (int r = 0; r < 32; r++) {
      float a8[8], x8[8];
      *(float4*)&a8[0] = *(float4*)&wexp[r][e0];
      *(float4*)&a8[4] = *(float4*)&wexp[r][e0 + 4];
      *(float4*)&x8[0] = *(float4*)&xt[r][d0];
      *(float4*)&x8[4] = *(float4*)&xt[r][d0 + 4];
#pragma unroll
      for (int i = 0; i < 8; i++)
#pragma unroll
        for (int j = 0; j < 8; j++) acc[i][j] += a8[i] * x8[j];
    }
  }
  float* outp = xs_part + ((size_t)ms * B + b) * E * D;
#pragma unroll
  for (int i = 0; i < 8; i++) {
    float* op = outp + (size_t)(e0 + i) * D + dg * 256 + d0;
    *(float4*)op       = *(float4*)&acc[i][0];
    *(float4*)(op + 4) = *(float4*)&acc[i][4];
  }
}

// ---- K5b: xs_f[e][d][b] = (sum_ms xs_part)/dsum. grid B*E=512, block 256 ----
__global__ __launch_bounds__(256) void k_xsred(const float* __restrict__ xs_part,
                                               const float* __restrict__ dsum,
                                               float* __restrict__ xs_f) {
  int blk = blockIdx.x;
  int b = blk >> 6, e = blk & 63;
  int t = threadIdx.x;
  float inv = 1.0f / dsum[b * 64 + e];
  const float2* pp = (const float2*)xs_part;
  size_t base = ((size_t)b * E + e) * (D / 2) + t;
  size_t slab = (size_t)B * E * (D / 2);
  float2 a = make_float2(0.f, 0.f);
  for (int ms = 0; ms < NSX; ms++) {
    float2 v = pp[(size_t)ms * slab + base];
    a.x += v.x; a.y += v.y;
  }
  int d = t * 2;
  xs_f[((size_t)e * D + d) * B + b]     = a.x * inv;
  xs_f[((size_t)e * D + d + 1) * B + b] = a.y * inv;
}

// ---- K6: h_part[ds][e][j][b] = sum_{d in split} xs_f[e][d][b]*w1[e][d][j] ----
// grid E*2*NK1=512, block 256; thread: 4 h-cols x 8 batches.
__global__ __launch_bounds__(256) void k_gemm1(const float* __restrict__ w1,
                                               const float* __restrict__ xs_f,
                                               float* __restrict__ h_part) {
  int blk = blockIdx.x;
  int ds = blk & 3, hs = (blk >> 2) & 1, e = blk >> 3;
  int t = threadIdx.x;
  int j0 = hs * 1024 + t * 4;
  const float* wp = w1 + ((size_t)e * D + ds * 128) * H + j0;
  const float* Xp = xs_f + ((size_t)e * D + ds * 128) * B;
  float acc[4][8];
#pragma unroll
  for (int i = 0; i < 4; i++)
#pragma unroll
    for (int j = 0; j < 8; j++) acc[i][j] = 0.f;
#pragma unroll 4
  for (int d = 0; d < 128; d++) {
    float4 w = *(const float4*)(wp + (size_t)d * H);
    const float* xb = Xp + d * 8;  // uniform address -> s_load
#pragma unroll
    for (int bb = 0; bb < 8; bb++) {
      float xv = xb[bb];
      acc[0][bb] += w.x * xv; acc[1][bb] += w.y * xv;
      acc[2][bb] += w.z * xv; acc[3][bb] += w.w * xv;
    }
  }
  float* op = h_part + (((size_t)ds * E + e) * H + j0) * B;
#pragma unroll
  for (int i = 0; i < 4; i++) {
    *(float4*)(op + i * 8)     = *(float4*)&acc[i][0];
    *(float4*)(op + i * 8 + 4) = *(float4*)&acc[i][4];
  }
}

// ---- K6b: hT[e][j][b] = gelu(sum_ds h_part + b1). grid E*8=512, block 256 ----
__global__ __launch_bounds__(256) void k_gelu(const float* __restrict__ h_part,
                                              const float* __restrict__ b1,
                                              float* __restrict__ hT) {
  int blk = blockIdx.x;
  int e = blk >> 3, jc = blk & 7;
  int t = threadIdx.x;
  int j = jc * 256 + t;
  float a[8];
#pragma unroll
  for (int k = 0; k < 8; k++) a[k] = 0.f;
  const float* pp = h_part + ((size_t)e * H + j) * B;
  for (int ds = 0; ds < NK1; ds++) {
    const float* q = pp + (size_t)ds * E * H * B;
#pragma unroll
    for (int k = 0; k < 8; k++) a[k] += q[k];
  }
  float bias = b1[e * H + j];
  float* op = hT + ((size_t)e * H + j) * B;
#pragma unroll
  for (int k = 0; k < 8; k++) {
    float v = a[k] + bias;
    op[k] = 0.5f * v * (1.0f + erff(v * 0.70710678118654752f));
  }
}

// ---- K7: ys_part[ks][e][d][b] = sum_{k in split} hT[e][k][b]*w2[e][k][d] ----
// grid E*NK2=512, block 256; thread: 2 d-cols x 8 batches.
__global__ __launch_bounds__(256) void k_gemm2(const float* __restrict__ w2,
                                               const float* __restrict__ hT,
                                               float* __restrict__ ys_part) {
  int blk = blockIdx.x;
  int ks = blk & 7, e = blk >> 3;
  int t = threadIdx.x;
  int c0 = t * 2;
  const float* wp = w2 + ((size_t)e * H + ks * 256) * D + c0;
  const float* Hp = hT + ((size_t)e * H + ks * 256) * B;
  float acc[2][8];
#pragma unroll
  for (int i = 0; i < 2; i++)
#pragma unroll
    for (int j = 0; j < 8; j++) acc[i][j] = 0.f;
#pragma unroll 4
  for (int k = 0; k < 256; k++) {
    float2 w = *(const float2*)(wp + (size_t)k * D);
    const float* hb = Hp + k * 8;  // uniform -> s_load
#pragma unroll
    for (int bb = 0; bb < 8; bb++) {
      acc[0][bb] += w.x * hb[bb];
      acc[1][bb] += w.y * hb[bb];
    }
  }
  float* op = ys_part + (((size_t)ks * E + e) * D + c0) * B;
  *(float4*)(op)      = *(float4*)&acc[0][0];
  *(float4*)(op + 4)  = *(float4*)&acc[0][4];
  *(float4*)(op + 8)  = *(float4*)&acc[1][0];
  *(float4*)(op + 12) = *(float4*)&acc[1][4];
}

// ---- K7b: ys_f[b][e][d] = sum_ks ys_part + b2[e][d]. grid E=64, block 256 ----
__global__ __launch_bounds__(256) void k_ysred(const float* __restrict__ ys_part,
                                               const float* __restrict__ b2,
                                               float* __restrict__ ys_f) {
  int e = blockIdx.x;
  int t = threadIdx.x;
#pragma unroll
  for (int k = 0; k < 4; k++) {
    int i4 = t + 256 * k;  // float4 index within [512 d][8 b] slab
    float4 a = make_float4(0.f, 0.f, 0.f, 0.f);
    for (int ks = 0; ks < NK2; ks++) {
      const float4* q = (const float4*)(ys_part + ((size_t)ks * E + e) * D * B);
      float4 v = q[i4];
      a.x += v.x; a.y += v.y; a.z += v.z; a.w += v.w;
    }
    int d = i4 >> 1, bh = (i4 & 1) * 4;
    float bias = b2[e * D + d];
    a.x += bias; a.y += bias; a.z += bias; a.w += bias;
    ys_f[((size_t)(bh + 0) * E + e) * D + d] = a.x;
    ys_f[((size_t)(bh + 1) * E + e) * D + d] = a.y;
    ys_f[((size_t)(bh + 2) * E + e) * D + d] = a.z;
    ys_f[((size_t)(bh + 3) * E + e) * D + d] = a.w;
  }
}

// ---- K8: y[b][m][d] = sum_e softmax_e(L[b][m][:])[e] * ys_f[b][e][d] ----
// grid B*32*4=1024 (128-row tile, 128-col group), block 256; thread tile 8r x 4d.
__global__ __launch_bounds__(256) void k_combine(const float* __restrict__ logits,
                                                 const float* __restrict__ ys_f,
                                                 float* __restrict__ y) {
  __shared__ float ysb[64][132];
  __shared__ float cT[64][68];
  __shared__ float red[64][4];
  __shared__ float gmx[64], gsm[64];
  int t = threadIdx.x;
  int blk = blockIdx.x;
  int dg = blk & 3, ms = (blk >> 2) & 31, b = blk >> 7;
  int m0 = ms * 128;
  // stage ys slice [64 e][128 d]
#pragma unroll
  for (int k = 0; k < 8; k++) {
    int f4 = t + 256 * k;
    int e = f4 >> 5, ci = f4 & 31;
    float4 v = *(const float4*)(ys_f + ((size_t)(b * E + e)) * D + dg * 128 + ci * 4);
    *(float4*)&ysb[e][ci * 4] = v;
  }
  int r0 = (t & 7) * 8;    // 0..56
  int d0 = (t >> 3) * 4;   // 0..124
  int row = t >> 2;        // 0..63
  int sub = t & 3;         // 4 threads per row, 16 e each
  for (int ch = 0; ch < 2; ch++) {
    int mr = m0 + ch * 64;
    float r16[16];
    const float* Lr = logits + ((size_t)(b * M + mr + row)) * E + sub * 16;
#pragma unroll
    for (int k = 0; k < 4; k++) *(float4*)&r16[k * 4] = *(const float4*)(Lr + k * 4);
    float lm = -1e30f;
#pragma unroll
    for (int k = 0; k < 16; k++) lm = fmaxf(lm, r16[k]);
    __syncthreads();  // also protects cT/ysb from previous-iter readers
    red[row][sub] = lm;
    __syncthreads();
    if (sub == 0) {
      float g = fmaxf(fmaxf(red[row][0], red[row][1]), fmaxf(red[row][2], red[row][3]));
      gmx[row] = g;
    }
    __syncthreads();
    float g = gmx[row];
    float ls = 0.f;
#pragma unroll
    for (int k = 0; k < 16; k++) {
      r16[k] = __expf(r16[k] - g);
      ls += r16[k];
    }
    __syncthreads();
    red[row][sub] = ls;
    __syncthreads();
    if (sub == 0)
      gsm[row] = 1.0f / (red[row][0] + red[row][1] + red[row][2] + red[row][3]);
    __syncthreads();
    float is = gsm[row];
#pragma unroll
    for (int k = 0; k < 16; k++) cT[sub * 16 + k][row] = r16[k] * is;
    __syncthreads();
    float acc[8][4];
#pragma unroll
    for (int i = 0; i < 8; i++)
#pragma unroll
      for (int j = 0; j < 4; j++) acc[i][j] = 0.f;
#pragma unroll 4
    for (int e = 0; e < 64; e++) {
      float c8[8], y4[4];
      *(float4*)&c8[0] = *(float4*)&cT[e][r0];
      *(float4*)&c8[4] = *(float4*)&cT[e][r0 + 4];
      *(float4*)&y4[0] = *(float4*)&ysb[e][d0];
#pragma unroll
      for (int i = 0; i < 8; i++)
#pragma unroll
        for (int j = 0; j < 4; j++) acc[i][j] += c8[i] * y4[j];
    }
#pragma unroll
    for (int i = 0; i < 8; i++) {
      float* op = y + ((size_t)(b * M + mr + r0 + i)) * D + dg * 128 + d0;
      *(float4*)op = *(float4*)&acc[i][0];
    }
  }
}

extern "C" void kernel_launch(void* const* d_in, const int* in_sizes, int n_in,
                              void* d_out, int out_size, void* d_ws, size_t ws_size,
                              hipStream_t stream) {
  const float* x     = (const float*)d_in[0];
  const float* phi   = (const float*)d_in[1];
  const float* scale = (const float*)d_in[2];
  const float* w1    = (const float*)d_in[3];
  const float* b1    = (const float*)d_in[4];
  const float* w2    = (const float*)d_in[5];
  const float* b2    = (const float*)d_in[6];
  float* y = (float*)d_out;
  float* ws = (float*)d_ws;
  (void)in_sizes; (void)n_in; (void)out_size; (void)ws_size;  // needs ws_size >= WS_FLOATS*4 (~74 MB)

  float* invn    = ws + OFF_INVN;
  float* phin    = ws + OFF_PHIN;
  float* logits  = ws + OFF_LOG;
  float* pmax    = ws + OFF_PMAX;
  float* psum    = ws + OFF_PSUM;
  float* dmax    = ws + OFF_DMAX;
  float* dsum    = ws + OFF_DSUM;
  float* xs_part = ws + OFF_XSP;
  float* xs_f    = ws + OFF_XSF;
  float* h_part  = ws + OFF_HP;
  float* hT      = ws + OFF_HT;
  float* ys_part = ws + OFF_YSP;
  float* ys_f    = ws + OFF_YSF;

  k_rownorm<<<(B * M) / 4, 256, 0, stream>>>(x, invn);
  k_phinorm<<<E, 256, 0, stream>>>(phi, scale, phin);
  k_logits<<<(B * M) / 128, 256, 0, stream>>>(x, phin, invn, logits);
  k_dstat<<<B * NSD, 256, 0, stream>>>(logits, pmax, psum);
  k_dstat2<<<B, 64, 0, stream>>>(pmax, psum, dmax, dsum);
  k_dispatch<<<B * NSX * 2, 256, 0, stream>>>(x, logits, invn, dmax, xs_part);
  k_xsred<<<B * E, 256, 0, stream>>>(xs_part, dsum, xs_f);
  k_gemm1<<<E * 2 * NK1, 256, 0, stream>>>(w1, xs_f, h_part);
  k_gelu<<<E * 8, 256, 0, stream>>>(h_part, b1, hT);
  k_gemm2<<<E * NK2, 256, 0, stream>>>(w2, hT, ys_part);
  k_ysred<<<E, 256, 0, stream>>>(ys_part, b2, ys_f);
  k_combine<<<B * 32 * 4, 256, 0, stream>>>(logits, ys_f, y);
}

// Round 2
// 296.744 us; speedup vs baseline: 1.0200x; 1.0200x over previous
//
#include <hip/hip_runtime.h>
#include <math.h>

// Soft-MoE forward, fp32. B=8, M=4096, D=512, E=64, P=1, H=2048.
// R2: fused rownorm+logits+dstat, inline dmax/dsum, float4 gemm2 (16 slabs).

namespace {
constexpr int B = 8, M = 4096, D = 512, E = 64, H = 2048;
constexpr int NSD = 32;   // logits/dstat m-splits (128 rows each)
constexpr int NSX = 32;   // dispatch m-splits
constexpr int NK1 = 4;    // gemm1 d-splits
constexpr int NK2 = 16;   // gemm2 k-slabs (8 blocks x 2 kk halves)

constexpr size_t OFF_INVN = 0;                            // B*M
constexpr size_t OFF_PHIN = OFF_INVN + (size_t)B * M;     // D*E
constexpr size_t OFF_LOG  = OFF_PHIN + (size_t)D * E;     // B*M*E
constexpr size_t OFF_PMAX = OFF_LOG  + (size_t)B * M * E; // B*NSD*E
constexpr size_t OFF_PSUM = OFF_PMAX + (size_t)B * NSD * E;
constexpr size_t OFF_XSP  = OFF_PSUM + (size_t)B * NSD * E; // NSX*B*E*D
constexpr size_t OFF_XSF  = OFF_XSP  + (size_t)NSX * B * E * D; // E*D*B
constexpr size_t OFF_HP   = OFF_XSF  + (size_t)E * D * B;   // NK1*E*H*B
constexpr size_t OFF_HT   = OFF_HP   + (size_t)NK1 * E * H * B; // E*H*B
constexpr size_t OFF_YSP  = OFF_HT   + (size_t)E * H * B;   // NK2*E*D*B
constexpr size_t OFF_YSF  = OFF_YSP  + (size_t)NK2 * E * D * B; // B*E*D
constexpr size_t WS_FLOATS = OFF_YSF + (size_t)E * D * B;   // ~95 MB
} // namespace

// ---- K2: phin = scale * l2norm(phi, axis=0). grid 64, block 256 ----
__global__ __launch_bounds__(256) void k_phinorm(const float* __restrict__ phi,
                                                 const float* __restrict__ scale,
                                                 float* __restrict__ phin) {
  int e = blockIdx.x;
  int t = threadIdx.x;
  float v0 = phi[(size_t)t * E + e];
  float v1 = phi[(size_t)(t + 256) * E + e];
  __shared__ float red[256];
  red[t] = v0 * v0 + v1 * v1;
  __syncthreads();
  for (int s = 128; s; s >>= 1) {
    if (t < s) red[t] += red[t + s];
    __syncthreads();
  }
  float inv = scale[0] / fmaxf(sqrtf(red[0]), 1e-12f);
  phin[(size_t)t * E + e]         = v0 * inv;
  phin[(size_t)(t + 256) * E + e] = v1 * inv;
}

// ---- K3: fused rownorm + logits + d-softmax partial stats ----
// grid 256 (128-row tiles), block 256; thread tile 8 rows x 4 e.
// Outputs: logits[row][e], invn[row], pmax/psum[blk][e] (per-128-row partials).
__global__ __launch_bounds__(256) void k_logits(const float* __restrict__ x,
                                                const float* __restrict__ phin,
                                                float* __restrict__ invn,
                                                float* __restrict__ logits,
                                                float* __restrict__ pmax,
                                                float* __restrict__ psum) {
  __shared__ float xT[16][132];
  __shared__ float ph[16][68];
  __shared__ float invs[128];
  __shared__ float sred[16][68];
  __shared__ float bmax[64];
  int t = threadIdx.x;
  int rowbase = blockIdx.x * 128;
  float acc[8][4];
#pragma unroll
  for (int i = 0; i < 8; i++)
#pragma unroll
    for (int j = 0; j < 4; j++) acc[i][j] = 0.f;
  int r0 = (t & 15) * 8;    // 0..120
  int e0 = (t >> 4) * 4;    // 0..60
  int srow = t >> 1;        // 0..127
  int sdh  = (t & 1) * 8;   // 0 or 8
  int pd = t >> 4;          // 0..15
  int pe = (t & 15) * 4;    // 0..60
  float ss = 0.f;           // sum of squares over this thread's half-row
  for (int d0 = 0; d0 < D; d0 += 16) {
    __syncthreads();
    const float4* xp = (const float4*)(x + (size_t)(rowbase + srow) * D + d0 + sdh);
    float4 a = xp[0], b = xp[1];
    ss += a.x * a.x + a.y * a.y + a.z * a.z + a.w * a.w +
          b.x * b.x + b.y * b.y + b.z * b.z + b.w * b.w;
    xT[sdh + 0][srow] = a.x; xT[sdh + 1][srow] = a.y;
    xT[sdh + 2][srow] = a.z; xT[sdh + 3][srow] = a.w;
    xT[sdh + 4][srow] = b.x; xT[sdh + 5][srow] = b.y;
    xT[sdh + 6][srow] = b.z; xT[sdh + 7][srow] = b.w;
    *(float4*)&ph[pd][pe] = *(const float4*)(phin + (size_t)(d0 + pd) * E + pe);
    __syncthreads();
#pragma unroll 4
    for (int kk = 0; kk < 16; kk++) {
      float a8[8], b4[4];
      *(float4*)&a8[0] = *(float4*)&xT[kk][r0];
      *(float4*)&a8[4] = *(float4*)&xT[kk][r0 + 4];
      *(float4*)&b4[0] = *(float4*)&ph[kk][e0];
#pragma unroll
      for (int i = 0; i < 8; i++)
#pragma unroll
        for (int j = 0; j < 4; j++) acc[i][j] += a8[i] * b4[j];
    }
  }
  // finish row norms (pair t, t^1 covers the full row)
  ss += __shfl_xor(ss, 1, 64);
  float iv = 1.0f / fmaxf(sqrtf(ss), 1e-12f);
  if ((t & 1) == 0) {
    invs[srow] = iv;
    invn[rowbase + srow] = iv;
  }
  __syncthreads();
  // scale + write logits
#pragma unroll
  for (int i = 0; i < 8; i++) {
    float inv = invs[r0 + i];
#pragma unroll
    for (int j = 0; j < 4; j++) acc[i][j] *= inv;
    float4 o;
    o.x = acc[i][0]; o.y = acc[i][1]; o.z = acc[i][2]; o.w = acc[i][3];
    *(float4*)(logits + (size_t)(rowbase + r0 + i) * E + e0) = o;
  }
  // block-partial softmax-over-m stats (max + sumexp over the 128 rows)
  int rg = t & 15;
#pragma unroll
  for (int j = 0; j < 4; j++) {
    float cm = acc[0][j];
#pragma unroll
    for (int i = 1; i < 8; i++) cm = fmaxf(cm, acc[i][j]);
    sred[rg][e0 + j] = cm;
  }
  __syncthreads();
  if (t < 64) {
    float g = sred[0][t];
#pragma unroll
    for (int i = 1; i < 16; i++) g = fmaxf(g, sred[i][t]);
    bmax[t] = g;
  }
  __syncthreads();
#pragma unroll
  for (int j = 0; j < 4; j++) {
    float bm = bmax[e0 + j];
    float s = 0.f;
#pragma unroll
    for (int i = 0; i < 8; i++) s += __expf(acc[i][j] - bm);
    sred[rg][e0 + j] = s;
  }
  __syncthreads();
  if (t < 64) {
    float s = 0.f;
#pragma unroll
    for (int i = 0; i < 16; i++) s += sred[i][t];
    pmax[(size_t)blockIdx.x * 64 + t] = bmax[t];
    psum[(size_t)blockIdx.x * 64 + t] = s;
  }
}

// ---- K5: dispatch partial: xs_part[ms][b][e][d] = sum_{m in split} exp(L-dmax)*xn ----
// grid B*NSX*2=512 (dg = 256-col half), block 256; thread tile 8e x 8d. dmax inline.
__global__ __launch_bounds__(256) void k_dispatch(const float* __restrict__ x,
                                                  const float* __restrict__ logits,
                                                  const float* __restrict__ invn,
                                                  const float* __restrict__ pmax,
                                                  float* __restrict__ xs_part) {
  __shared__ float wexp[32][68];
  __shared__ float xt[32][260];
  __shared__ float dmx[64];
  int t = threadIdx.x;
  int blk = blockIdx.x;
  int dg = blk & 1, ms = (blk >> 1) & 31, b = blk >> 6;
  int m0 = ms * 128;
  if (t < 64) {
    float g = pmax[((size_t)b * NSD) * 64 + t];
    for (int s = 1; s < NSD; s++)
      g = fmaxf(g, pmax[((size_t)(b * NSD + s)) * 64 + t]);
    dmx[t] = g;
  }
  float acc[8][8];
#pragma unroll
  for (int i = 0; i < 8; i++)
#pragma unroll
    for (int j = 0; j < 8; j++) acc[i][j] = 0.f;
  int e0 = (t & 7) * 8, d0 = (t >> 3) * 8;
  for (int c = 0; c < 4; c++) {
    int mr = m0 + c * 32;
    __syncthreads();
#pragma unroll
    for (int k = 0; k < 8; k++) {  // stage exp weights [32][64]
      int idx = t + 256 * k;
      int r = idx >> 6, e = idx & 63;
      wexp[r][e] = __expf(logits[((size_t)(b * M + mr + r)) * E + e] - dmx[e]);
    }
#pragma unroll
    for (int k = 0; k < 8; k++) {  // stage xn tile [32][256]
      int f4 = t + 256 * k;
      int r = f4 >> 6, ci = f4 & 63;
      float4 v = *(const float4*)(x + ((size_t)(b * M + mr + r)) * D + dg * 256 + ci * 4);
      float iv = invn[b * M + mr + r];
      v.x *= iv; v.y *= iv; v.z *= iv; v.w *= iv;
      *(float4*)&xt[r][ci * 4] = v;
    }
    __syncthreads();
#pragma unroll 2
    for (int r = 0; r < 32; r++) {
      float a8[8], x8[8];
      *(float4*)&a8[0] = *(float4*)&wexp[r][e0];
      *(float4*)&a8[4] = *(float4*)&wexp[r][e0 + 4];
      *(float4*)&x8[0] = *(float4*)&xt[r][d0];
      *(float4*)&x8[4] = *(float4*)&xt[r][d0 + 4];
#pragma unroll
      for (int i = 0; i < 8; i++)
#pragma unroll
        for (int j = 0; j < 8; j++) acc[i][j] += a8[i] * x8[j];
    }
  }
  float* outp = xs_part + ((size_t)ms * B + b) * E * D;
#pragma unroll
  for (int i = 0; i < 8; i++) {
    float* op = outp + (size_t)(e0 + i) * D + dg * 256 + d0;
    *(float4*)op       = *(float4*)&acc[i][0];
    *(float4*)(op + 4) = *(float4*)&acc[i][4];
  }
}

// ---- K5b: xs_f[e][d][b] = (sum_ms xs_part)/dsum, dsum inline. grid B*E=512 ----
__global__ __launch_bounds__(256) void k_xsred(const float* __restrict__ xs_part,
                                               const float* __restrict__ pmax,
                                               const float* __restrict__ psum,
                                               float* __restrict__ xs_f) {
  int blk = blockIdx.x;
  int b = blk >> 6, e = blk & 63;
  int t = threadIdx.x;
  // dsum from partial stats (uniform across block)
  float gm = -1e30f;
  for (int s = 0; s < NSD; s++)
    gm = fmaxf(gm, pmax[((size_t)(b * NSD + s)) * 64 + e]);
  float gs = 0.f;
  for (int s = 0; s < NSD; s++)
    gs += psum[((size_t)(b * NSD + s)) * 64 + e] *
          __expf(pmax[((size_t)(b * NSD + s)) * 64 + e] - gm);
  float inv = 1.0f / gs;
  const float2* pp = (const float2*)xs_part;
  size_t base = ((size_t)b * E + e) * (D / 2) + t;
  size_t slab = (size_t)B * E * (D / 2);
  float2 a = make_float2(0.f, 0.f);
  for (int ms = 0; ms < NSX; ms++) {
    float2 v = pp[(size_t)ms * slab + base];
    a.x += v.x; a.y += v.y;
  }
  int d = t * 2;
  xs_f[((size_t)e * D + d) * B + b]     = a.x * inv;
  xs_f[((size_t)e * D + d + 1) * B + b] = a.y * inv;
}

// ---- K6: h_part[ds][e][j][b] = sum_{d in split} xs_f[e][d][b]*w1[e][d][j] ----
// grid E*2*NK1=512, block 256; thread: 4 h-cols x 8 batches.
__global__ __launch_bounds__(256) void k_gemm1(const float* __restrict__ w1,
                                               const float* __restrict__ xs_f,
                                               float* __restrict__ h_part) {
  int blk = blockIdx.x;
  int ds = blk & 3, hs = (blk >> 2) & 1, e = blk >> 3;
  int t = threadIdx.x;
  int j0 = hs * 1024 + t * 4;
  const float* wp = w1 + ((size_t)e * D + ds * 128) * H + j0;
  const float* Xp = xs_f + ((size_t)e * D + ds * 128) * B;
  float acc[4][8];
#pragma unroll
  for (int i = 0; i < 4; i++)
#pragma unroll
    for (int j = 0; j < 8; j++) acc[i][j] = 0.f;
#pragma unroll 8
  for (int d = 0; d < 128; d++) {
    float4 w = *(const float4*)(wp + (size_t)d * H);
    const float* xb = Xp + d * 8;  // uniform address -> s_load
#pragma unroll
    for (int bb = 0; bb < 8; bb++) {
      float xv = xb[bb];
      acc[0][bb] += w.x * xv; acc[1][bb] += w.y * xv;
      acc[2][bb] += w.z * xv; acc[3][bb] += w.w * xv;
    }
  }
  float* op = h_part + (((size_t)ds * E + e) * H + j0) * B;
#pragma unroll
  for (int i = 0; i < 4; i++) {
    *(float4*)(op + i * 8)     = *(float4*)&acc[i][0];
    *(float4*)(op + i * 8 + 4) = *(float4*)&acc[i][4];
  }
}

// ---- K6b: hT[e][j][b] = gelu(sum_ds h_part + b1). grid E*8=512, block 256 ----
__global__ __launch_bounds__(256) void k_gelu(const float* __restrict__ h_part,
                                              const float* __restrict__ b1,
                                              float* __restrict__ hT) {
  int blk = blockIdx.x;
  int e = blk >> 3, jc = blk & 7;
  int t = threadIdx.x;
  int j = jc * 256 + t;
  float a[8];
#pragma unroll
  for (int k = 0; k < 8; k++) a[k] = 0.f;
  const float* pp = h_part + ((size_t)e * H + j) * B;
  for (int ds = 0; ds < NK1; ds++) {
    const float* q = pp + (size_t)ds * E * H * B;
#pragma unroll
    for (int k = 0; k < 8; k++) a[k] += q[k];
  }
  float bias = b1[e * H + j];
  float* op = hT + ((size_t)e * H + j) * B;
#pragma unroll
  for (int k = 0; k < 8; k++) {
    float v = a[k] + bias;
    op[k] = 0.5f * v * (1.0f + erff(v * 0.70710678118654752f));
  }
}

// ---- K7: ys_part[ks*2+kk][e][d][b] = sum_{k in sub-split} hT[e][k][b]*w2[e][k][d] ----
// grid E*8=512, block 256; thread: kk=t>>7, 4 d-cols x 8 batches, float4 loads.
__global__ __launch_bounds__(256) void k_gemm2(const float* __restrict__ w2,
                                               const float* __restrict__ hT,
                                               float* __restrict__ ys_part) {
  int blk = blockIdx.x;
  int ks = blk & 7, e = blk >> 3;
  int t = threadIdx.x;
  int kk = t >> 7, dq = t & 127;
  int d0 = dq * 4;
  const float* wp = w2 + ((size_t)e * H + ks * 256 + kk) * D + d0;
  const float* Hp = hT + ((size_t)e * H + ks * 256 + kk) * B;
  float acc[4][8];
#pragma unroll
  for (int i = 0; i < 4; i++)
#pragma unroll
    for (int j = 0; j < 8; j++) acc[i][j] = 0.f;
#pragma unroll 4
  for (int i = 0; i < 128; i++) {
    float4 w = *(const float4*)(wp + (size_t)i * 2 * D);
    const float* hb = Hp + (size_t)i * 2 * B;
    float h8[8];
    *(float4*)&h8[0] = *(const float4*)(hb);
    *(float4*)&h8[4] = *(const float4*)(hb + 4);
#pragma unroll
    for (int bb = 0; bb < 8; bb++) {
      acc[0][bb] += w.x * h8[bb];
      acc[1][bb] += w.y * h8[bb];
      acc[2][bb] += w.z * h8[bb];
      acc[3][bb] += w.w * h8[bb];
    }
  }
  float* op = ys_part + (((size_t)(ks * 2 + kk) * E + e) * D + d0) * B;
#pragma unroll
  for (int i = 0; i < 4; i++) {
    *(float4*)(op + i * 8)     = *(float4*)&acc[i][0];
    *(float4*)(op + i * 8 + 4) = *(float4*)&acc[i][4];
  }
}

// ---- K7b: ys_f[b][e][d] = sum_ks ys_part + b2[e][d]. grid E*4=256, block 256 ----
__global__ __launch_bounds__(256) void k_ysred(const float* __restrict__ ys_part,
                                               const float* __restrict__ b2,
                                               float* __restrict__ ys_f) {
  int e = blockIdx.x >> 2, kq = blockIdx.x & 3;
  int t = threadIdx.x;
  int i4 = kq * 256 + t;  // float4 index within [512 d][8 b] slab
  float4 a = make_float4(0.f, 0.f, 0.f, 0.f);
  for (int ks = 0; ks < NK2; ks++) {
    const float4* q = (const float4*)(ys_part + ((size_t)ks * E + e) * D * B);
    float4 v = q[i4];
    a.x += v.x; a.y += v.y; a.z += v.z; a.w += v.w;
  }
  int d = i4 >> 1, bh = (i4 & 1) * 4;
  float bias = b2[e * D + d];
  a.x += bias; a.y += bias; a.z += bias; a.w += bias;
  ys_f[((size_t)(bh + 0) * E + e) * D + d] = a.x;
  ys_f[((size_t)(bh + 1) * E + e) * D + d] = a.y;
  ys_f[((size_t)(bh + 2) * E + e) * D + d] = a.z;
  ys_f[((size_t)(bh + 3) * E + e) * D + d] = a.w;
}

// ---- K8: y[b][m][d] = sum_e softmax_e(L[b][m][:])[e] * ys_f[b][e][d] ----
// grid B*32*4=1024, block 256; thread tile 8r x 4d.
__global__ __launch_bounds__(256) void k_combine(const float* __restrict__ logits,
                                                 const float* __restrict__ ys_f,
                                                 float* __restrict__ y) {
  __shared__ float ysb[64][132];
  __shared__ float cT[64][68];
  __shared__ float red[64][4];
  __shared__ float gmx[64], gsm[64];
  int t = threadIdx.x;
  int blk = blockIdx.x;
  int dg = blk & 3, ms = (blk >> 2) & 31, b = blk >> 7;
  int m0 = ms * 128;
#pragma unroll
  for (int k = 0; k < 8; k++) {
    int f4 = t + 256 * k;
    int e = f4 >> 5, ci = f4 & 31;
    float4 v = *(const float4*)(ys_f + ((size_t)(b * E + e)) * D + dg * 128 + ci * 4);
    *(float4*)&ysb[e][ci * 4] = v;
  }
  int r0 = (t & 7) * 8;    // 0..56
  int d0 = (t >> 3) * 4;   // 0..124
  int row = t >> 2;        // 0..63
  int sub = t & 3;         // 4 threads per row, 16 e each
  for (int ch = 0; ch < 2; ch++) {
    int mr = m0 + ch * 64;
    float r16[16];
    const float* Lr = logits + ((size_t)(b * M + mr + row)) * E + sub * 16;
#pragma unroll
    for (int k = 0; k < 4; k++) *(float4*)&r16[k * 4] = *(const float4*)(Lr + k * 4);
    float lm = -1e30f;
#pragma unroll
    for (int k = 0; k < 16; k++) lm = fmaxf(lm, r16[k]);
    __syncthreads();  // also protects cT/ysb from previous-iter readers
    red[row][sub] = lm;
    __syncthreads();
    if (sub == 0) {
      float g = fmaxf(fmaxf(red[row][0], red[row][1]), fmaxf(red[row][2], red[row][3]));
      gmx[row] = g;
    }
    __syncthreads();
    float g = gmx[row];
    float ls = 0.f;
#pragma unroll
    for (int k = 0; k < 16; k++) {
      r16[k] = __expf(r16[k] - g);
      ls += r16[k];
    }
    __syncthreads();
    red[row][sub] = ls;
    __syncthreads();
    if (sub == 0)
      gsm[row] = 1.0f / (red[row][0] + red[row][1] + red[row][2] + red[row][3]);
    __syncthreads();
    float is = gsm[row];
#pragma unroll
    for (int k = 0; k < 16; k++) cT[sub * 16 + k][row] = r16[k] * is;
    __syncthreads();
    float acc[8][4];
#pragma unroll
    for (int i = 0; i < 8; i++)
#pragma unroll
      for (int j = 0; j < 4; j++) acc[i][j] = 0.f;
#pragma unroll 4
    for (int e = 0; e < 64; e++) {
      float c8[8], y4[4];
      *(float4*)&c8[0] = *(float4*)&cT[e][r0];
      *(float4*)&c8[4] = *(float4*)&cT[e][r0 + 4];
      *(float4*)&y4[0] = *(float4*)&ysb[e][d0];
#pragma unroll
      for (int i = 0; i < 8; i++)
#pragma unroll
        for (int j = 0; j < 4; j++) acc[i][j] += c8[i] * y4[j];
    }
#pragma unroll
    for (int i = 0; i < 8; i++) {
      float* op = y + ((size_t)(b * M + mr + r0 + i)) * D + dg * 128 + d0;
      *(float4*)op = *(float4*)&acc[i][0];
    }
  }
}

extern "C" void kernel_launch(void* const* d_in, const int* in_sizes, int n_in,
                              void* d_out, int out_size, void* d_ws, size_t ws_size,
                              hipStream_t stream) {
  const float* x     = (const float*)d_in[0];
  const float* phi   = (const float*)d_in[1];
  const float* scale = (const float*)d_in[2];
  const float* w1    = (const float*)d_in[3];
  const float* b1    = (const float*)d_in[4];
  const float* w2    = (const float*)d_in[5];
  const float* b2    = (const float*)d_in[6];
  float* y = (float*)d_out;
  float* ws = (float*)d_ws;
  (void)in_sizes; (void)n_in; (void)out_size; (void)ws_size;

  float* invn    = ws + OFF_INVN;
  float* phin    = ws + OFF_PHIN;
  float* logits  = ws + OFF_LOG;
  float* pmax    = ws + OFF_PMAX;
  float* psum    = ws + OFF_PSUM;
  float* xs_part = ws + OFF_XSP;
  float* xs_f    = ws + OFF_XSF;
  float* h_part  = ws + OFF_HP;
  float* hT      = ws + OFF_HT;
  float* ys_part = ws + OFF_YSP;
  float* ys_f    = ws + OFF_YSF;

  k_phinorm<<<E, 256, 0, stream>>>(phi, scale, phin);
  k_logits<<<(B * M) / 128, 256, 0, stream>>>(x, phin, invn, logits, pmax, psum);
  k_dispatch<<<B * NSX * 2, 256, 0, stream>>>(x, logits, invn, pmax, xs_part);
  k_xsred<<<B * E, 256, 0, stream>>>(xs_part, pmax, psum, xs_f);
  k_gemm1<<<E * 2 * NK1, 256, 0, stream>>>(w1, xs_f, h_part);
  k_gelu<<<E * 8, 256, 0, stream>>>(h_part, b1, hT);
  k_gemm2<<<E * 8, 256, 0, stream>>>(w2, hT, ys_part);
  k_ysred<<<E * 4, 256, 0, stream>>>(ys_part, b2, ys_f);
  k_combine<<<B * 32 * 4, 256, 0, stream>>>(logits, ys_f, y);
}